// Round 6
// baseline (365.161 us; speedup 1.0000x reference)
//
#include <hip/hip_runtime.h>
#include <hip/hip_bf16.h>
#include <stdint.h>

// out[b][co][y][x0] = sum_{ci,ky,kx} x[b][ci][(y+ky-3)%256][(x0+kx-3)%256] * d[b][co][ci][ky][kx]
// Per (b,row) GEMM: tmp[u][n=co*8+kx] = sum_{ci,ky} X[ci][(y+ky-3)%256][u] * w[co][ci][ky][kx]
// epilogue: out[x0] = sum_kx tmp[(x0+kx-3)&255][co*8+kx].  MFMA 32x32x16 bf16 (verified r3-r5).
// v4: R=16 rows/block (halo amp 1.75->1.375), ci split across 2 blocks/tile (grid stays 256),
// partial f32 outputs combined via d_ws + combine kernel (fallback: memset + atomicAdd).
// CI_CHUNK=4 with k-slot remap (ci_local=j&3, ky=ks2*4+lh*2+(j>>2)) on BOTH A and B.

constexpr int NB = 8, CIN = 64, HH = 256, WW = 256, CO = 3, KK = 7;
constexpr int R = 16;            // output rows per block
constexpr int XROWS = 22;        // staged rows r=0..21 (input y0-3 .. y0+18)
constexpr int CI_CHUNK = 4;
constexpr int NCH = 8;           // 32 ci per block / 4
constexpr int XUNITS = XROWS * 256;        // 8B units per X buffer (5632)
constexpr int OUTSZ = NB * CO * HH * WW;   // 1572864

typedef short bf16x4 __attribute__((ext_vector_type(4)));
typedef short bf16x8 __attribute__((ext_vector_type(8)));
typedef float f32x16 __attribute__((ext_vector_type(16)));

__device__ inline uint16_t f2bf(float f) {
    union { __hip_bfloat16 h; uint16_t u; } cv;
    cv.h = __float2bfloat16(f);
    return cv.u;
}
__device__ inline int uswz(int u) { return u ^ ((u >> 4) & 15); }  // unit swizzle

// LDS: Xl[2][22*256] 8B-units = 90112 B | Bl 16 frags * 64 lanes * 16 B = 16384 B (106496)
// epilogue tmp f32[4][256][33] = 135168 B aliases everything.
__global__ __launch_bounds__(1024, 4)
void conv_mfma_v4(const float* __restrict__ x, const float* __restrict__ d,
                  float* __restrict__ outp, float* __restrict__ wsp, int useAtomic) {
    __shared__ char smem[135168];
    uint16_t* Xl  = (uint16_t*)smem;                 // unit = 4 bf16 (ci 0..3)
    uint16_t* Bl  = (uint16_t*)(smem + 90112);
    float*    tmp = (float*)smem;                    // [4][256][33]

    const int tid  = threadIdx.x;
    const int lane = tid & 63, wv = tid >> 6;        // 16 waves
    const int y_t  = wv;                             // wave owns row y0 + y_t
    const int l31  = lane & 31, lh = lane >> 5;

    // XCD swizzle: XCD (blk&7) owns image b; its 32 blocks = 16 tiles x 2 ci-halves.
    const int blk  = blockIdx.x;
    const int b    = blk & 7;
    const int t16  = (blk >> 3) & 15;
    const int half = blk >> 7;
    const int y0   = t16 * R;
    const int ciBase = half * 32;

    const float* xb = x + (size_t)b * CIN * HH * WW;
    const float* db = d + (size_t)b * CO * CIN * KK * KK;

    f32x16 acc[8];
    #pragma unroll
    for (int m = 0; m < 8; ++m)
        #pragma unroll
        for (int i = 0; i < 16; ++i) acc[m][i] = 0.f;

    // ---- stage chunk c (4 ci) into buffer buf ----
    auto stageX = [&](int c, int buf) {
        const int cb = ciBase + c * CI_CHUNK;
        uint16_t* dst = Xl + (size_t)buf * XUNITS * 4;
        for (int it = tid; it < XROWS * 64; it += 1024) {
            const int r = it >> 6, q = it & 63;
            const int row = (y0 + r - 3) & (HH - 1);
            const float* p = xb + ((size_t)cb * HH + row) * WW + q * 4;
            float4 v0 = *reinterpret_cast<const float4*>(p);
            float4 v1 = *reinterpret_cast<const float4*>(p + (size_t)HH * WW);
            float4 v2 = *reinterpret_cast<const float4*>(p + (size_t)2 * HH * WW);
            float4 v3 = *reinterpret_cast<const float4*>(p + (size_t)3 * HH * WW);
            #pragma unroll
            for (int t = 0; t < 4; ++t) {
                const int us = uswz(q * 4 + t);
                uint2 pk;
                pk.x = (uint32_t)f2bf(((const float*)&v0)[t]) | ((uint32_t)f2bf(((const float*)&v1)[t]) << 16);
                pk.y = (uint32_t)f2bf(((const float*)&v2)[t]) | ((uint32_t)f2bf(((const float*)&v3)[t]) << 16);
                *reinterpret_cast<uint2*>(dst + (size_t)(r * 256 + us) * 4) = pk;
            }
        }
    };

    // ---- compute chunk c: 2 k-steps (ky quads), 8 m-frags ----
    auto compute = [&](int c, int buf) {
        const uint16_t* Xb = Xl + (size_t)buf * XUNITS * 4;
        #pragma unroll
        for (int ks2 = 0; ks2 < 2; ++ks2) {
            const int fi = c * 2 + ks2;
            const bf16x8 bfrag = *reinterpret_cast<const bf16x8*>(&Bl[(size_t)(fi * 64 + lane) * 8]);
            const int r1 = y_t + ks2 * 4 + lh * 2;   // <= 21, never wraps
            int r2 = r1 + 1;                         // ==22 only y_t=15,ky=7 (zero weight)
            if (r2 >= XROWS) r2 = 0;
            #pragma unroll
            for (int m = 0; m < 8; ++m) {
                const int us = uswz(m * 32 + l31);
                const bf16x4 lo = *reinterpret_cast<const bf16x4*>(&Xb[((size_t)r1 * 256 + us) * 4]);
                const bf16x4 hi = *reinterpret_cast<const bf16x4*>(&Xb[((size_t)r2 * 256 + us) * 4]);
                bf16x8 a;
                a[0] = lo[0]; a[1] = lo[1]; a[2] = lo[2]; a[3] = lo[3];
                a[4] = hi[0]; a[5] = hi[1]; a[6] = hi[2]; a[7] = hi[3];
                acc[m] = __builtin_amdgcn_mfma_f32_32x32x16_bf16(a, bfrag, acc[m], 0, 0, 0);
            }
        }
    };

    // ---- prologue: X chunk 0 + all 16 B-frags (k-slot remap matching A) ----
    stageX(0, 0);
    {
        const int s = tid;                           // 1024 slots = 16 frags x 64 lanes
        const int fi = s >> 6, ln = s & 63;
        const int c = fi >> 1, ks2 = fi & 1;
        const int h = ln >> 5, n = ln & 31;
        const int co = n >> 3, kx = n & 7;
        const int cb = ciBase + c * CI_CHUNK;
        uint16_t vals[8];
        #pragma unroll
        for (int j = 0; j < 8; ++j) {
            const int ky = ks2 * 4 + h * 2 + (j >> 2);
            float v = 0.f;
            if (co < CO && kx < KK && ky < KK)
                v = db[((size_t)co * CIN + (cb + (j & 3))) * (KK * KK) + ky * KK + kx];
            vals[j] = f2bf(v);
        }
        uint4 pk;
        pk.x = (uint32_t)vals[0] | ((uint32_t)vals[1] << 16);
        pk.y = (uint32_t)vals[2] | ((uint32_t)vals[3] << 16);
        pk.z = (uint32_t)vals[4] | ((uint32_t)vals[5] << 16);
        pk.w = (uint32_t)vals[6] | ((uint32_t)vals[7] << 16);
        *reinterpret_cast<uint4*>(&Bl[(size_t)(fi * 64 + ln) * 8]) = pk;
    }

    // ---- main loop: barrier per chunk; stage(c+1) overlaps compute(c) ----
    for (int c = 0; c < NCH; ++c) {
        __syncthreads();
        if (c + 1 < NCH) stageX(c + 1, (c + 1) & 1);
        compute(c, c & 1);
    }

    // ---- epilogue: 4 rounds x 4 rows ----
    for (int p = 0; p < 4; ++p) {
        __syncthreads();
        if ((y_t >> 2) == p) {
            const int rr = y_t & 3;
            #pragma unroll
            for (int m = 0; m < 8; ++m)
                #pragma unroll
                for (int reg = 0; reg < 16; ++reg) {
                    const int rowloc = (reg & 3) + 8 * (reg >> 2) + 4 * lh;
                    const int u = m * 32 + rowloc;
                    tmp[((size_t)rr * 256 + u) * 33 + l31] = acc[m][reg];
                }
        }
        __syncthreads();
        for (int it = tid; it < 4 * CO * 256; it += 1024) {   // 3072 items
            const int rr  = it / (CO * 256);
            const int rem = it - rr * (CO * 256);
            const int co  = rem >> 8, x0 = rem & 255;
            float s = 0.f;
            #pragma unroll
            for (int kx = 0; kx < 7; ++kx)
                s += tmp[((size_t)rr * 256 + ((x0 + kx - 3) & 255)) * 33 + co * 8 + kx];
            const size_t oidx = ((size_t)(b * CO + co) * HH + (y0 + p * 4 + rr)) * WW + x0;
            if (useAtomic) atomicAdd(&outp[oidx], s);
            else           wsp[(size_t)half * OUTSZ + oidx] = s;
        }
    }
}

__global__ __launch_bounds__(256)
void combine_halves(const float* __restrict__ ws, float* __restrict__ outp) {
    const int i = blockIdx.x * 256 + threadIdx.x;        // float4 index
    if (i < OUTSZ / 4) {
        const float4 a = reinterpret_cast<const float4*>(ws)[i];
        const float4 c = reinterpret_cast<const float4*>(ws + OUTSZ)[i];
        reinterpret_cast<float4*>(outp)[i] =
            make_float4(a.x + c.x, a.y + c.y, a.z + c.z, a.w + c.w);
    }
}

extern "C" void kernel_launch(void* const* d_in, const int* in_sizes, int n_in,
                              void* d_out, int out_size, void* d_ws, size_t ws_size,
                              hipStream_t stream) {
    const float* x = (const float*)d_in[0];
    const float* d = (const float*)d_in[1];
    float* outp = (float*)d_out;
    const bool useWs = ws_size >= (size_t)2 * OUTSZ * sizeof(float);
    if (!useWs)
        hipMemsetAsync(d_out, 0, (size_t)OUTSZ * sizeof(float), stream);
    conv_mfma_v4<<<dim3(256), 1024, 0, stream>>>(x, d, outp, (float*)d_ws,
                                                 useWs ? 0 : 1);
    if (useWs)
        combine_halves<<<dim3(OUTSZ / 4 / 256), 256, 0, stream>>>((float*)d_ws, outp);
}

// Round 8
// 52.038 us; speedup vs baseline: 7.0172x; 7.0172x over previous
//
#include <hip/hip_runtime.h>
#include <hip/hip_bf16.h>
#include <stdint.h>

// out[b][co][y][x0] = sum_{ci,ky,kx} x[b][ci][(y+ky-3)%256][(x0+kx-3)%256] * d[b][co][ci][ky][kx]
// Rolling-window design: block = (image b, ci-quarter, 32-row strip).
// LDS ring of 10 row-slabs [256 u][16 ci] bf16; each input row staged ONCE (amp 38/32).
// Per iter t: compute output rows y0+2t, y0+2t+1 COMPLETELY (K = 16ci x 8ky = 128,
// 8 MFMA 32x32x16 per wave, acc = 16 VGPR), staging rows 2t+8,2t+9 for later iters.
// v5 fix vs r7: prologue stages ALL 10 slabs (t=0 read of slot 8 was uninitialized LDS
// -> NaN x zero-weight = NaN); main-loop staging starts at t=1.
// k-slot mapping (ky = ks2*2 + lh, 8 consecutive ci per frag) identical to r3-r5 verified scheme.

constexpr int NB = 8, CIN = 64, HH = 256, WW = 256, CO = 3, KK = 7;
constexpr int STRIP = 32;          // output rows per block
constexpr int RING  = 10;          // row slabs in ring
constexpr int SLABB = 256 * 16 * 2;            // bytes per slab (8192)
constexpr int CIQ   = 16;          // ci per block
constexpr size_t OUTSZ = (size_t)NB * CO * HH * WW;

typedef short bf16x8 __attribute__((ext_vector_type(8)));
typedef float f32x16 __attribute__((ext_vector_type(16)));

__device__ inline uint16_t f2bf(float f) {
    union { __hip_bfloat16 h; uint16_t u; } cv;
    cv.h = __float2bfloat16(f);
    return cv.u;
}

// LDS: ring 10*8192 = 81920 | B 8 frags*64 lanes*16B = 8192 | tmp f32[2][256][33] = 67584
// total 157696 <= 160 KiB
__global__ __launch_bounds__(1024, 4)
void conv_roll(const float* __restrict__ x, const float* __restrict__ d,
               float* __restrict__ outp) {
    __shared__ char smem[157696];
    float* tmp = (float*)(smem + 90112);

    const int tid  = threadIdx.x;
    const int lane = tid & 63, wv = tid >> 6;      // 16 waves
    const int l31  = lane & 31, lh = lane >> 5;
    const int t_row = wv >> 3, m = wv & 7;         // wave -> (row parity, m-frag)

    const int blk   = blockIdx.x;
    const int cmb   = blk & 31, strip = blk >> 5;  // XCD = blk%8 (combo-pinned)
    const int b     = cmb >> 2, ciq = cmb & 3;
    const int y0    = strip * STRIP;
    const int ciBase = ciq * CIQ;

    const float* xb = x + (size_t)b * CIN * HH * WW;
    const float* db = d + (size_t)b * CO * CIN * KK * KK;

    // ---- one staged item: 4 u-cols x 4 ci of input row (slab jj) ----
    auto stage_item = [&](int jj, int uq, int cq) {
        const int grow = (y0 + jj - 3) & (HH - 1);
        const float* p = xb + ((size_t)(ciBase + cq * 4) * HH + grow) * WW + uq * 4;
        float4 v0 = *reinterpret_cast<const float4*>(p);
        float4 v1 = *reinterpret_cast<const float4*>(p + (size_t)HH * WW);
        float4 v2 = *reinterpret_cast<const float4*>(p + (size_t)2 * HH * WW);
        float4 v3 = *reinterpret_cast<const float4*>(p + (size_t)3 * HH * WW);
        char* dst = smem + (jj % RING) * SLABB + (uq * 4) * 32 + cq * 8;
        #pragma unroll
        for (int t4 = 0; t4 < 4; ++t4) {
            uint2 pk;
            pk.x = (uint32_t)f2bf(((const float*)&v0)[t4]) | ((uint32_t)f2bf(((const float*)&v1)[t4]) << 16);
            pk.y = (uint32_t)f2bf(((const float*)&v2)[t4]) | ((uint32_t)f2bf(((const float*)&v3)[t4]) << 16);
            *reinterpret_cast<uint2*>(dst + t4 * 32) = pk;
        }
    };

    // ---- prologue: B frags (8 x 64 lanes), k-mapping matches A ----
    if (tid < 512) {
        const int fi = tid >> 6, ln = tid & 63;
        const int cih = fi >> 2, ks2 = fi & 3;
        const int h = ln >> 5, n = ln & 31;
        const int ky = ks2 * 2 + h, co = n >> 3, kx = n & 7;
        uint16_t vals[8];
        #pragma unroll
        for (int j = 0; j < 8; ++j) {
            float v = 0.f;
            if (co < CO && kx < KK && ky < KK)
                v = db[((size_t)co * CIN + ciBase + cih * 8 + j) * (KK * KK) + ky * KK + kx];
            vals[j] = f2bf(v);
        }
        uint4 pk;
        pk.x = (uint32_t)vals[0] | ((uint32_t)vals[1] << 16);
        pk.y = (uint32_t)vals[2] | ((uint32_t)vals[3] << 16);
        pk.z = (uint32_t)vals[4] | ((uint32_t)vals[5] << 16);
        pk.w = (uint32_t)vals[6] | ((uint32_t)vals[7] << 16);
        *reinterpret_cast<uint4*>(smem + 81920 + (size_t)tid * 16) = pk;
    }
    // ---- prologue: ALL 10 slabs (input rows y0-3 .. y0+6) ----
    #pragma unroll
    for (int k = 0; k < 3; ++k) {
        const int it = tid + k * 1024;             // 2560 items
        if (it < RING * 256) {
            const int jj = it >> 8, rem = it & 255;
            stage_item(jj, rem >> 2, rem & 3);
        }
    }
    __syncthreads();

    // hoist B fragments to registers (reused all 16 iters)
    bf16x8 bfr[8];
    #pragma unroll
    for (int fi = 0; fi < 8; ++fi)
        bfr[fi] = *reinterpret_cast<const bf16x8*>(smem + 81920 + fi * 1024 + lane * 16);

    const int aoff = (m * 32 + l31) * 32;          // A byte offset within slab

    int base = 0;                                  // (2t) % RING
    for (int t = 0; t < 16; ++t) {
        f32x16 acc;
        #pragma unroll
        for (int i = 0; i < 16; ++i) acc[i] = 0.f;

        // issue next-rows' global loads early (drain under MFMAs)
        float4 sv0, sv1, sv2, sv3;
        int sjj = -1, suq = 0, scq = 0;
        if (t >= 1 && t < 15 && tid < 512) {
            const int tr2 = tid >> 8, rem = tid & 255;
            suq = rem >> 2; scq = rem & 3;
            sjj = 2 * t + 8 + tr2;
            const int grow = (y0 + sjj - 3) & (HH - 1);
            const float* p = xb + ((size_t)(ciBase + scq * 4) * HH + grow) * WW + suq * 4;
            sv0 = *reinterpret_cast<const float4*>(p);
            sv1 = *reinterpret_cast<const float4*>(p + (size_t)HH * WW);
            sv2 = *reinterpret_cast<const float4*>(p + (size_t)2 * HH * WW);
            sv3 = *reinterpret_cast<const float4*>(p + (size_t)3 * HH * WW);
        }

        // compute rows y0+2t+t_row: 8 k-steps (K=128)
        #pragma unroll
        for (int fi = 0; fi < 8; ++fi) {
            const int cih = fi >> 2, ks2 = fi & 3;
            const int ky = ks2 * 2 + lh;
            int s = base + t_row + ky;             // j = 2t + t_row + ky
            if (s >= RING) s -= RING;              // wrap: stale slab, zero-weight only
            const bf16x8 af = *reinterpret_cast<const bf16x8*>(
                smem + s * SLABB + aoff + cih * 16);
            acc = __builtin_amdgcn_mfma_f32_32x32x16_bf16(af, bfr[fi], acc, 0, 0, 0);
        }

        // late half of staging: convert + LDS write (slots hold consumed rows 2t-2,2t-1)
        if (sjj >= 0) {
            char* dst = smem + (sjj % RING) * SLABB + (suq * 4) * 32 + scq * 8;
            #pragma unroll
            for (int t4 = 0; t4 < 4; ++t4) {
                uint2 pk;
                pk.x = (uint32_t)f2bf(((const float*)&sv0)[t4]) | ((uint32_t)f2bf(((const float*)&sv1)[t4]) << 16);
                pk.y = (uint32_t)f2bf(((const float*)&sv2)[t4]) | ((uint32_t)f2bf(((const float*)&sv3)[t4]) << 16);
                *reinterpret_cast<uint2*>(dst + t4 * 32) = pk;
            }
        }

        // dump acc -> tmp (verified C/D layout)
        #pragma unroll
        for (int reg = 0; reg < 16; ++reg) {
            const int rowloc = (reg & 3) + 8 * (reg >> 2) + 4 * lh;
            tmp[((size_t)t_row * 256 + m * 32 + rowloc) * 33 + l31] = acc[reg];
        }
        __syncthreads();                           // tmp + ring writes visible

        // kx-reduce + atomic combine (1536 outputs)
        {
            int it = tid;
            #pragma unroll
            for (int rep = 0; rep < 2; ++rep) {
                if (it < 2 * CO * 256) {
                    const int tr = it >= CO * 256;
                    const int rem = it - tr * (CO * 256);
                    const int co = rem >> 8, x0 = rem & 255;
                    float s = 0.f;
                    #pragma unroll
                    for (int kx = 0; kx < 7; ++kx)
                        s += tmp[((size_t)tr * 256 + ((x0 + kx - 3) & 255)) * 33 + co * 8 + kx];
                    atomicAdd(&outp[((size_t)(b * CO + co) * HH + (y0 + 2 * t + tr)) * WW + x0], s);
                }
                it += 1024;
            }
        }
        __syncthreads();                           // reduce done before next dump/stage

        base += 2;
        if (base >= RING) base -= RING;
    }
}

extern "C" void kernel_launch(void* const* d_in, const int* in_sizes, int n_in,
                              void* d_out, int out_size, void* d_ws, size_t ws_size,
                              hipStream_t stream) {
    const float* x = (const float*)d_in[0];
    const float* d = (const float*)d_in[1];
    float* outp = (float*)d_out;
    hipMemsetAsync(d_out, 0, OUTSZ * sizeof(float), stream);
    conv_roll<<<dim3(256), 1024, 0, stream>>>(x, d, outp);
}

// Round 9
// 51.244 us; speedup vs baseline: 7.1260x; 1.0155x over previous
//
#include <hip/hip_runtime.h>
#include <hip/hip_bf16.h>
#include <stdint.h>

// out[b][co][y][x0] = sum_{ci,ky,kx} x[b][ci][(y+ky-3)%256][(x0+kx-3)%256] * d[b][co][ci][ky][kx]
// v6 "strip-partials": block = (img b, 4-row input strip). Stages ONLY its 4 rows
// (x read exactly once, amp 1.0), computes partials for out rows [y0-3, y0+6]
// (o = r+6-ky; ky NOT in MFMA K-dim; K = ci only, 4 epochs x 16 ci).
// Partials -> d_ws; combine kernel sums 2-3 strips per out row. No atomics, no memset.
// MFMA 32x32x16 bf16, A/B k-slot = (half lh, 8 ci) and C/D mapping verified r3-r5.

constexpr int NB=8, CIN=64, HH=256, WW=256, CO=3, KK=7;
constexpr int RS=4;                  // staged input rows per block
constexpr int ORS=RS+6;              // 10 partial out rows
constexpr int NSTRIP=HH/RS;          // 64
constexpr int EPOCHS=4, CIC=16;      // 4 epochs x 16 ci
constexpr int XHALF = RS*256*16;     // bytes per lh-half per buffer (16384)
constexpr int XBYTES = 2*XHALF;      // 32768 per buffer
constexpr int BOFF = 2*XBYTES;       // 65536 (X double buffer)
constexpr int NBFRAG = KK*EPOCHS;    // 28 B fragments
constexpr int SMEMSZ = BOFF + NBFRAG*64*16;          // 94208; tmp f32[2][256][33]=67584 aliases
constexpr size_t WS_STRIDE = (size_t)ORS*CO*256;     // floats per block partial

typedef short bf16x8 __attribute__((ext_vector_type(8)));
typedef float f32x16 __attribute__((ext_vector_type(16)));

__device__ inline uint16_t f2bf(float f){ union{__hip_bfloat16 h; uint16_t u;}c; c.h=__float2bfloat16(f); return c.u; }
__device__ inline int uswz(int u){ return u ^ ((u>>3)&7); }   // involution; spreads addr[6:4]

__global__ __launch_bounds__(512, 2)
void conv_strip(const float* __restrict__ x, const float* __restrict__ d,
                float* __restrict__ ws) {
    __shared__ char smem[SMEMSZ];
    float* tmp = (float*)smem;

    const int tid=threadIdx.x, lane=tid&63;
    const int l31=lane&31, lh=lane>>5, m=tid>>6;     // wave = m-frag (u block m*32)

    const int blk=blockIdx.x, b=blk&7, strip=blk>>3; // XCD (blk%8) pinned to image b
    const int y0=strip*RS;

    const float* xb = x + (size_t)b*CIN*HH*WW;
    const float* db = d + (size_t)b*CO*CIN*KK*KK;

    // ---- stage B: 28 frags x 64 lanes x 16B; k-slot (lh half, 8 ci) matches A ----
    #pragma unroll
    for (int k=0;k<4;++k){
        const int s = tid + k*512;
        if (s < NBFRAG*64){
            const int fi=s>>6, ln=s&63;
            const int ky=fi>>2, e=fi&3;              // fi = ky*4 + e
            const int n=ln&31, hh2=ln>>5;
            const int co=n>>3, kx=n&7;
            uint16_t vals[8];
            #pragma unroll
            for(int j=0;j<8;++j){
                float v=0.f;
                if(co<CO && kx<KK)
                    v = db[((size_t)co*CIN + e*CIC + hh2*8 + j)*(KK*KK) + ky*KK + kx];
                vals[j]=f2bf(v);
            }
            uint4 pk;
            pk.x=(uint32_t)vals[0]|((uint32_t)vals[1]<<16);
            pk.y=(uint32_t)vals[2]|((uint32_t)vals[3]<<16);
            pk.z=(uint32_t)vals[4]|((uint32_t)vals[5]<<16);
            pk.w=(uint32_t)vals[6]|((uint32_t)vals[7]<<16);
            *reinterpret_cast<uint4*>(smem + BOFF + (size_t)(fi*64+ln)*16) = pk;
        }
    }

    f32x16 acc[ORS];
    #pragma unroll
    for(int o=0;o<ORS;++o)
        #pragma unroll
        for(int i=0;i<16;++i) acc[o][i]=0.f;

    // per-thread stage item: (r = tid>>8 + 2*t2, cq = (tid>>6)&3, uq = tid&63)
    auto issue_loads = [&](int e, float4 (&st)[2][4]){
        const int c0 = e*CIC;
        #pragma unroll
        for(int t2=0;t2<2;++t2){
            const int r = (tid>>8) + t2*2;
            const int cq = (tid>>6)&3, uq = tid&63;
            const float* p = xb + ((size_t)(c0+cq*4)*HH + (y0+r))*WW + uq*4;
            #pragma unroll
            for(int j=0;j<4;++j)
                st[t2][j] = *reinterpret_cast<const float4*>(p + (size_t)j*HH*WW);
        }
    };
    auto write_stage = [&](int buf, const float4 (&st)[2][4]){
        char* base = smem + buf*XBYTES;
        #pragma unroll
        for(int t2=0;t2<2;++t2){
            const int r = (tid>>8) + t2*2;
            const int cq = (tid>>6)&3, uq = tid&63;
            char* hbase = base + (cq>>1)*XHALF;      // ci-half = lh half
            const int sub = (cq&1)*8;                // 8B slot within 16B unit
            #pragma unroll
            for(int t4=0;t4<4;++t4){
                const int us = uswz(uq*4+t4);
                uint2 pk;
                pk.x=(uint32_t)f2bf(((const float*)&st[t2][0])[t4])|((uint32_t)f2bf(((const float*)&st[t2][1])[t4])<<16);
                pk.y=(uint32_t)f2bf(((const float*)&st[t2][2])[t4])|((uint32_t)f2bf(((const float*)&st[t2][3])[t4])<<16);
                *reinterpret_cast<uint2*>(hbase + (size_t)(r*256+us)*16 + sub) = pk;
            }
        }
    };

    float4 st[2][4];
    issue_loads(0, st);
    write_stage(0, st);
    __syncthreads();

    for(int e=0;e<EPOCHS;++e){
        float4 nst[2][4];
        if(e+1<EPOCHS) issue_loads(e+1, nst);        // T14: issue early
        {
            const char* Xb = smem + (e&1)*XBYTES + lh*XHALF;
            bf16x8 bf[KK];
            #pragma unroll
            for(int ky=0;ky<KK;++ky)
                bf[ky] = *reinterpret_cast<const bf16x8*>(
                    smem + BOFF + (size_t)((ky*EPOCHS+e)*64 + lane)*16);
            #pragma unroll
            for(int r=0;r<RS;++r){
                const int us = uswz(m*32 + l31);
                const bf16x8 af = *reinterpret_cast<const bf16x8*>(Xb + (size_t)(r*256+us)*16);
                #pragma unroll
                for(int ky=0;ky<KK;++ky)
                    acc[r+6-ky] = __builtin_amdgcn_mfma_f32_32x32x16_bf16(
                        af, bf[ky], acc[r+6-ky], 0,0,0);
            }
        }
        if(e+1<EPOCHS) write_stage((e+1)&1, nst);    // disjoint buffer: no pre-barrier
        __syncthreads();                             // writes visible for next epoch
    }

    // ---- epilogue: 5 passes x 2 out rows; tmp[2][256][33] aliases X region ----
    #pragma unroll
    for(int p=0;p<5;++p){
        #pragma unroll
        for(int rr=0;rr<2;++rr){
            const int o = 2*p+rr;
            #pragma unroll
            for(int reg=0;reg<16;++reg){
                const int rowloc=(reg&3)+8*(reg>>2)+4*lh;
                tmp[(size_t)(rr*256 + m*32 + rowloc)*33 + l31] = acc[o][reg];
            }
        }
        __syncthreads();
        if(tid < 384){
            const int rr = tid/192, rem = tid%192;
            const int co = rem>>6, uq = rem&63;
            #pragma unroll
            for(int t4=0;t4<4;++t4){
                const int u = uq + t4*64;            // stride-64: conflict-free tmp reads
                float s=0.f;
                #pragma unroll
                for(int kx=0;kx<KK;++kx)
                    s += tmp[(size_t)(rr*256 + ((u+kx-3)&255))*33 + co*8 + kx];
                ws[(size_t)blk*WS_STRIDE + ((size_t)(2*p+rr)*CO + co)*256 + u] = s;
            }
        }
        __syncthreads();
    }
}

__global__ __launch_bounds__(256)
void combine_strips(const float* __restrict__ ws, float* __restrict__ outp){
    const int idx = blockIdx.x*256 + threadIdx.x;    // float4 index; out[b][co][y][u]
    const int uq = idx & 63;
    const int y  = (idx>>6) & 255;
    const int cb = idx >> 14;
    const int co = cb % 3, b = cb / 3;
    const int s0 = y>>2, ph = y&3;
    const float4* w0 = reinterpret_cast<const float4*>(
        ws + (size_t)(s0*8+b)*WS_STRIDE + ((size_t)(ph+3)*CO+co)*256) + uq;
    float4 v = *w0;
    if(ph<=2){
        const int s=(s0+NSTRIP-1)&(NSTRIP-1);
        const float4 a = *(reinterpret_cast<const float4*>(
            ws + (size_t)(s*8+b)*WS_STRIDE + ((size_t)(ph+7)*CO+co)*256) + uq);
        v.x+=a.x; v.y+=a.y; v.z+=a.z; v.w+=a.w;
    }
    if(ph>=1){
        const int s=(s0+1)&(NSTRIP-1);
        const float4 a = *(reinterpret_cast<const float4*>(
            ws + (size_t)(s*8+b)*WS_STRIDE + ((size_t)(ph-1)*CO+co)*256) + uq);
        v.x+=a.x; v.y+=a.y; v.z+=a.z; v.w+=a.w;
    }
    reinterpret_cast<float4*>(outp)[idx] = v;
}

extern "C" void kernel_launch(void* const* d_in, const int* in_sizes, int n_in,
                              void* d_out, int out_size, void* d_ws, size_t ws_size,
                              hipStream_t stream) {
    const float* x = (const float*)d_in[0];
    const float* d = (const float*)d_in[1];
    float* outp = (float*)d_out;
    float* ws   = (float*)d_ws;      // needs 512*ORS*CO*256*4 = 15.7 MB (ws is ~512 MB)
    conv_strip<<<dim3(NB*NSTRIP), 512, 0, stream>>>(x, d, ws);
    combine_strips<<<dim3(NB*CO*HH*WW/4/256), 256, 0, stream>>>(ws, outp);
}